// Round 20
// baseline (574.993 us; speedup 1.0000x reference)
//
#include <hip/hip_runtime.h>
#include <hip/hip_bf16.h>
#include <cstdint>

// Problem constants (from reference)
#define TT     2048   // tokens
#define KSEL   6      // experts per token
#define DMODEL 2048   // model dim
#define DINTER 1408   // moe intermediate dim
#define NE     16     // routed experts
#define PMAX   (TT * KSEL)

typedef short bf16x8 __attribute__((ext_vector_type(8)));
typedef float f32x4 __attribute__((ext_vector_type(4)));
typedef unsigned short u16;
typedef u16 u16x8 __attribute__((ext_vector_type(8)));

__device__ __forceinline__ u16 f2bf(float f) {
  union { float f; unsigned u; } v; v.f = f;
  return (u16)((v.u + 0x7FFFu + ((v.u >> 16) & 1u)) >> 16);  // RNE
}
__device__ __forceinline__ float bf2f(u16 h) {
  union { unsigned u; float f; } v; v.u = (unsigned)h << 16; return v.f;
}

__device__ __forceinline__ void gl2lds16(const void* g, void* l) {
  __builtin_amdgcn_global_load_lds((const __attribute__((address_space(1))) void*)g,
                                   (__attribute__((address_space(3))) void*)l,
                                   16, 0, 0);
}

// gate_w[t,e] = sum_k weights[t,k]*(indices[t,k]==e); count routed (t,e) pairs
__global__ void k_gate(const float* __restrict__ w, const int* __restrict__ idx,
                       float* __restrict__ gate_w, int* __restrict__ counts) {
  int g = blockIdx.x * 256 + threadIdx.x;  // T*E threads
  int t = g >> 4, e = g & 15;
  const int* ip = idx + t * KSEL;
  const float* wp = w + t * KSEL;
  float s = 0.f;
#pragma unroll
  for (int k = 0; k < KSEL; ++k) s += (ip[k] == e) ? wp[k] : 0.f;
  gate_w[g] = s;
  if (s != 0.f) atomicAdd(counts + e, 1);
}

__global__ void k_scan(const int* __restrict__ counts, int* __restrict__ offs) {
  if (threadIdx.x == 0 && blockIdx.x == 0) {
    int r = 0;
#pragma unroll
    for (int e = 0; e < NE; ++e) { offs[e] = r; r += counts[e]; }
    offs[NE] = r;
  }
}

// fill slot lists + per-token slot map (for the combine epilogue)
__global__ void k_fill(const float* __restrict__ gate_w, const int* __restrict__ offs,
                       int* __restrict__ cursor, int* __restrict__ slot_tok,
                       float* __restrict__ slot_gate, int* __restrict__ tcnt,
                       int* __restrict__ tok_slots) {
  int g = blockIdx.x * 256 + threadIdx.x;
  int t = g >> 4, e = g & 15;
  float s = gate_w[g];
  if (s != 0.f) {
    int p = atomicAdd(cursor + e, 1);
    int sl = offs[e] + p;
    slot_tok[sl] = t;
    slot_gate[sl] = s;
    int q = atomicAdd(tcnt + t, 1);
    tok_slots[t * KSEL + q] = sl;
  }
}

// fp32->bf16 cast for x + FIRST HALF of Wg, Wu (the rest is cast inside the
// gemm1A/gemm1B launches as embedded role blocks).
#define XV8   (TT * DMODEL / 8)                      // 524288 items
#define WV8   (NE * DINTER * DMODEL / 8)             // 5767168 items (full tensor)
#define WHI   (WV8 / 2)                              // 2883584 items (half tensor)
__global__ void k_cast_h1(const float* __restrict__ x,  u16* __restrict__ xb,
                          const float* __restrict__ wg, u16* __restrict__ wgb,
                          const float* __restrict__ wu, u16* __restrict__ wub) {
  const int total = XV8 + 2 * WHI;
  int stride = gridDim.x * 256;
  for (int i = blockIdx.x * 256 + threadIdx.x; i < total; i += stride) {
    const float* src; u16* dst; int j;
    if (i < XV8)            { src = x;  dst = xb;  j = i; }
    else if (i < XV8 + WHI) { src = wg; dst = wgb; j = i - XV8; }
    else                    { src = wu; dst = wub; j = i - XV8 - WHI; }
    const float4* p = (const float4*)src + (size_t)j * 2;
    float4 v0 = p[0], v1 = p[1];
    u16x8 o;
    o[0] = f2bf(v0.x); o[1] = f2bf(v0.y); o[2] = f2bf(v0.z); o[3] = f2bf(v0.w);
    o[4] = f2bf(v1.x); o[5] = f2bf(v1.y); o[6] = f2bf(v1.z); o[7] = f2bf(v1.w);
    *(u16x8*)(dst + (size_t)j * 8) = o;
  }
}

// ---------------------------------------------------------------------------
// LDS XOR swizzle (G4 / rule #21): rows are 64 bf16 = 8 16B-units; write side
// pre-permutes the GLOBAL source unit (u' = u ^ (row&7), LDS dest linear per
// gl2lds HW rule), read side applies the same XOR -> conflict-free (R6: 0).
// Register budget (m69): 128 AGPR acc + ~108 VGPR = 2 waves/SIMD for gemm1.
//
// GEMM1 half-launch (R19-validated embed mechanism, split by expert half):
//   grid = 2112 = 264 octets; octets q%3==2 are CAST role (704 blocks, two
//   352-block spans given by (castS0,castD0,castO0)/(castS1,castD1,castO1));
//   the rest decode to 1408 gemm ids covering experts [eBase, eBase+8).
//   Octet interleave keeps b%8 == g%8 (XCD-chunk property preserved).
//   gemm1A: experts 0-7,  casts Wg[8:16], Wu[8:16] (consumed by gemm1B).
//   gemm1B: experts 8-15, casts Wd (consumed by gemm2).
// ---------------------------------------------------------------------------
__global__ __launch_bounds__(256, 2) void k_gemm1(
    const u16* __restrict__ xb, const u16* __restrict__ wgb, const u16* __restrict__ wub,
    const float* __restrict__ castS0, u16* __restrict__ castD0, int castO0,
    const float* __restrict__ castS1, u16* __restrict__ castD1, int castO1,
    int eBase,
    const int* __restrict__ slot_tok, const float* __restrict__ slot_gate,
    const int* __restrict__ offs, const int* __restrict__ counts,
    u16* __restrict__ act) {
  int bq = blockIdx.x >> 3, br = blockIdx.x & 7;
  if (bq % 3 == 2) {
    // ---- cast role: 704 blocks x 8192 items x 8 elems ----
    int c = (bq / 3) * 8 + br;                 // [0, 704)
    const float* src = (c < 352) ? castS0 : castS1;
    u16* dst        = (c < 352) ? castD0 : castD1;
    int base        = ((c < 352) ? castO0 : castO1) + (c % 352) * 8192;
#pragma unroll 4
    for (int it = 0; it < 32; ++it) {
      int j = base + it * 256 + threadIdx.x;
      const float4* p = (const float4*)src + (size_t)j * 2;
      float4 v0 = p[0], v1 = p[1];
      u16x8 o;
      o[0] = f2bf(v0.x); o[1] = f2bf(v0.y); o[2] = f2bf(v0.z); o[3] = f2bf(v0.w);
      o[4] = f2bf(v1.x); o[5] = f2bf(v1.y); o[6] = f2bf(v1.z); o[7] = f2bf(v1.w);
      *(u16x8*)(dst + (size_t)j * 8) = o;
    }
    return;
  }
  int g = ((bq / 3) * 2 + (bq % 3)) * 8 + br;  // [0, 1408)
  // XCD-chunked swizzle over 1408 ids: w = (g&7)*176 + g>>3
  int w = (g & 7) * 176 + (g >> 3);
  int mt = w & 15, rest = w >> 4;              // rest in [0, 88)
  int it = rest % 11, e = eBase + rest / 11;

  int mcount = counts[e];
  if (mt * 128 >= mcount) return;
  int mrem = mcount - mt * 128; if (mrem > 128) mrem = 128;
  int slotBase = offs[e] + mt * 128;
  int iBase = it * 128;

  __shared__ u16 sA[128 * 64];
  __shared__ u16 sG[128 * 64];
  __shared__ u16 sU[128 * 64];
  __shared__ int tokLds[128];
  __shared__ float gateLds[128];

  int tid = threadIdx.x;
  if (tid < 128) {
    int rl = tid < mrem ? tid : 0;        // pad rows clamp to row 0 (valid addr)
    tokLds[tid] = slot_tok[slotBase + rl];
    gateLds[tid] = (tid < mrem) ? slot_gate[slotBase + rl] : 0.f;
  }
  __syncthreads();

  int wv = tid >> 6, lane = tid & 63;
  // staging: 16 chunks of 1KB (8 rows x 128B); linear LDS dest, swizzled source
  const u16 *aSrc[4], *gSrc[4], *uSrc[4];
  u16 *aDst[4], *gDst[4], *uDst[4];
  const u16* gBase = wgb + ((size_t)e * DINTER + iBase) * DMODEL;
  const u16* uBase = wub + ((size_t)e * DINTER + iBase) * DMODEL;
  int r8 = lane >> 3;
  int colOff = ((lane & 7) ^ r8) * 8;   // swizzled 16B-unit within the row
#pragma unroll
  for (int i2 = 0; i2 < 4; ++i2) {
    int chunk = wv * 4 + i2;
    int row = chunk * 8 + r8;
    aSrc[i2] = xb + (size_t)tokLds[row] * DMODEL + colOff;
    gSrc[i2] = gBase + (size_t)row * DMODEL + colOff;
    uSrc[i2] = uBase + (size_t)row * DMODEL + colOff;
    aDst[i2] = sA + chunk * 512;
    gDst[i2] = sG + chunk * 512;
    uDst[i2] = sU + chunk * 512;
  }

  f32x4 accg[4][4] = {};
  f32x4 accu[4][4] = {};
  int fr = lane & 15, fq = lane >> 4;
  int wr = (wv >> 1) * 64, wc = (wv & 1) * 64;

  for (int kb = 0; kb < DMODEL / 64; ++kb) {
    int kOff = kb * 64;
    __syncthreads();
#pragma unroll
    for (int i2 = 0; i2 < 4; ++i2) {
      gl2lds16(aSrc[i2] + kOff, aDst[i2]);
      gl2lds16(gSrc[i2] + kOff, gDst[i2]);
      gl2lds16(uSrc[i2] + kOff, uDst[i2]);
    }
    __syncthreads();
#pragma unroll
    for (int kf = 0; kf < 2; ++kf) {
      bf16x8 af[4], bg[4], bu[4];
#pragma unroll
      for (int mf = 0; mf < 4; ++mf) {
        int row = wr + mf * 16 + fr;
        int cu = ((kf * 4 + fq) ^ (row & 7)) * 8;
        af[mf] = *(const bf16x8*)&sA[row * 64 + cu];
      }
#pragma unroll
      for (int nf = 0; nf < 4; ++nf) {
        int row = wc + nf * 16 + fr;
        int cu = ((kf * 4 + fq) ^ (row & 7)) * 8;
        bg[nf] = *(const bf16x8*)&sG[row * 64 + cu];
        bu[nf] = *(const bf16x8*)&sU[row * 64 + cu];
      }
#pragma unroll
      for (int mf = 0; mf < 4; ++mf)
#pragma unroll
        for (int nf = 0; nf < 4; ++nf) {
          accg[mf][nf] = __builtin_amdgcn_mfma_f32_16x16x32_bf16(af[mf], bg[nf], accg[mf][nf], 0, 0, 0);
          accu[mf][nf] = __builtin_amdgcn_mfma_f32_16x16x32_bf16(af[mf], bu[nf], accu[mf][nf], 0, 0, 0);
        }
    }
  }
  // epilogue: act = silu(g)*u*gate -> bf16  (D layout: col=lane&15, row=(lane>>4)*4+r)
#pragma unroll
  for (int mf = 0; mf < 4; ++mf)
#pragma unroll
    for (int nf = 0; nf < 4; ++nf)
#pragma unroll
      for (int r = 0; r < 4; ++r) {
        int row = wr + mf * 16 + fq * 4 + r;
        if (row < mrem) {
          float gv = accg[mf][nf][r], uv = accu[mf][nf][r];
          float a = gv / (1.f + __expf(-gv)) * uv * gateLds[row];
          act[(size_t)(slotBase + row) * DINTER + iBase + wc + nf * 16 + fr] = f2bf(a);
        }
      }
}

// GEMM2: per-slot contribution out[slot,:] = act[slot,:] @ Wd[e,:,:]^T.
// Combine path (outb != nullptr): plain bf16 stores, NO atomics; k_combine
// sums each token's <=6 slots. Fallback (outb == nullptr): fp32 atomicAdd.
__global__ __launch_bounds__(256, 3) void k_gemm2(
    const u16* __restrict__ act, const u16* __restrict__ wdb,
    const int* __restrict__ slot_tok, const int* __restrict__ offs,
    const int* __restrict__ counts, float* __restrict__ y,
    u16* __restrict__ outb) {
  // grid flat = 16(mt) x 16(dt) x 16(e) = 4096 = 8*512
  int b = blockIdx.x;
  int w = (b & 7) * 512 + (b >> 3);
  int mt = w & 15, rest = w >> 4;
  int dt = rest & 15, e = rest >> 4;

  int mcount = counts[e];
  if (mt * 128 >= mcount) return;
  int mrem = mcount - mt * 128; if (mrem > 128) mrem = 128;
  int slotBase = offs[e] + mt * 128;
  int dBase = dt * 128;

  __shared__ u16 sA[128 * 64];
  __shared__ u16 sB[128 * 64];
  __shared__ int tokLds[128];

  int tid = threadIdx.x;
  if (tid < 128) tokLds[tid] = slot_tok[slotBase + (tid < mrem ? tid : 0)];
  __syncthreads();

  int wv = tid >> 6, lane = tid & 63;
  const u16 *aSrc[4], *bSrc[4];
  u16 *aDst[4], *bDst[4];
  const u16* bBase = wdb + ((size_t)e * DMODEL + dBase) * DINTER;
  int r8 = lane >> 3;
  int colOff = ((lane & 7) ^ r8) * 8;   // swizzled 16B-unit
#pragma unroll
  for (int i2 = 0; i2 < 4; ++i2) {
    int chunk = wv * 4 + i2;
    int row = chunk * 8 + r8;
    aSrc[i2] = act + (size_t)(slotBase + row) * DINTER + colOff;  // act padded rows
    bSrc[i2] = bBase + (size_t)row * DINTER + colOff;
    aDst[i2] = sA + chunk * 512;
    bDst[i2] = sB + chunk * 512;
  }

  f32x4 acc[4][4] = {};
  int fr = lane & 15, fq = lane >> 4;
  int wr = (wv >> 1) * 64, wc = (wv & 1) * 64;

  for (int kb = 0; kb < DINTER / 64; ++kb) {
    int kOff = kb * 64;
    __syncthreads();
#pragma unroll
    for (int i2 = 0; i2 < 4; ++i2) {
      gl2lds16(aSrc[i2] + kOff, aDst[i2]);
      gl2lds16(bSrc[i2] + kOff, bDst[i2]);
    }
    __syncthreads();
#pragma unroll
    for (int kf = 0; kf < 2; ++kf) {
      bf16x8 af[4], bb[4];
#pragma unroll
      for (int mf = 0; mf < 4; ++mf) {
        int row = wr + mf * 16 + fr;
        int cu = ((kf * 4 + fq) ^ (row & 7)) * 8;
        af[mf] = *(const bf16x8*)&sA[row * 64 + cu];
      }
#pragma unroll
      for (int nf = 0; nf < 4; ++nf) {
        int row = wc + nf * 16 + fr;
        int cu = ((kf * 4 + fq) ^ (row & 7)) * 8;
        bb[nf] = *(const bf16x8*)&sB[row * 64 + cu];
      }
#pragma unroll
      for (int mf = 0; mf < 4; ++mf)
#pragma unroll
        for (int nf = 0; nf < 4; ++nf)
          acc[mf][nf] = __builtin_amdgcn_mfma_f32_16x16x32_bf16(af[mf], bb[nf], acc[mf][nf], 0, 0, 0);
    }
  }
#pragma unroll
  for (int mf = 0; mf < 4; ++mf)
#pragma unroll
    for (int nf = 0; nf < 4; ++nf)
#pragma unroll
      for (int r = 0; r < 4; ++r) {
        int row = wr + mf * 16 + fq * 4 + r;
        if (row < mrem) {
          int col = dBase + wc + nf * 16 + fr;
          if (outb) {
            outb[(size_t)(slotBase + row) * DMODEL + col] = f2bf(acc[mf][nf][r]);
          } else {
            atomicAdd(y + (size_t)tokLds[row] * DMODEL + col, acc[mf][nf][r]);
          }
        }
      }
}

// combine: y[t,:] = sum over token t's slots of out[slot,:]
__global__ void k_combine(const u16* __restrict__ outb, const int* __restrict__ tok_slots,
                          const int* __restrict__ tcnt, float* __restrict__ y) {
  int idx = blockIdx.x * 256 + threadIdx.x;   // TT * DMODEL/8 threads
  int t = idx >> 8;                           // DMODEL/8 = 256 per token
  int d0 = (idx & 255) * 8;
  int n = tcnt[t];
  float s[8] = {};
  for (int j = 0; j < n; ++j) {
    int sl = tok_slots[t * KSEL + j];
    u16x8 v = *(const u16x8*)(outb + (size_t)sl * DMODEL + d0);
#pragma unroll
    for (int q = 0; q < 8; ++q) s[q] += bf2f(v[q]);
  }
  float4* yp = (float4*)(y + (size_t)t * DMODEL + d0);
  yp[0] = make_float4(s[0], s[1], s[2], s[3]);
  yp[1] = make_float4(s[4], s[5], s[6], s[7]);
}

extern "C" void kernel_launch(void* const* d_in, const int* in_sizes, int n_in,
                              void* d_out, int out_size, void* d_ws, size_t ws_size,
                              hipStream_t stream) {
  const float* x       = (const float*)d_in[0];
  const float* weights = (const float*)d_in[1];
  const int*   indices = (const int*)d_in[2];
  const float* Wg      = (const float*)d_in[3];
  const float* Wu      = (const float*)d_in[4];
  const float* Wd      = (const float*)d_in[5];
  float* y = (float*)d_out;

  const size_t WELEM = (size_t)NE * DINTER * DMODEL;  // 46.1M elems per weight tensor
  const int HOFF = (int)WHI;                          // half-tensor offset in items

  char* ws = (char*)d_ws;
  size_t o = 0;
  float* gate_w = (float*)(ws + o); o += (size_t)TT * NE * 4;
  size_t ctrlOff = o;
  int* counts = (int*)(ws + o);
  int* offs   = (int*)(ws + o + 64);
  int* cursor = (int*)(ws + o + 192);
  int* tcnt   = (int*)(ws + o + 256);            // TT ints
  int* tok_slots = (int*)(ws + o + 256 + TT * 4); // TT*KSEL ints
  size_t ctrlZero = 256 + TT * 4;                // zero counts..tcnt
  o += 256 + TT * 4 + (size_t)TT * KSEL * 4;
  int*   slot_tok  = (int*)(ws + o);   o += (size_t)PMAX * 4;
  float* slot_gate = (float*)(ws + o); o += (size_t)PMAX * 4;
  u16* xb  = (u16*)(ws + o); o += (size_t)TT * DMODEL * 2;
  u16* act = (u16*)(ws + o); o += (size_t)(PMAX + 128) * DINTER * 2; // +128 pad rows
  u16* wgb = (u16*)(ws + o); o += WELEM * 2;
  u16* wub = (u16*)(ws + o); o += WELEM * 2;
  u16* wdb = (u16*)(ws + o); o += WELEM * 2;
  u16* outb = (u16*)(ws + o);
  size_t oEnd = o + (size_t)PMAX * DMODEL * 2;   // +50.3 MB for combine path
  bool useCombine = (ws_size >= oEnd);
  (void)in_sizes; (void)n_in;

  if (!useCombine) hipMemsetAsync(d_out, 0, (size_t)out_size * 4, stream);
  hipMemsetAsync(ws + ctrlOff, 0, ctrlZero, stream);

  k_gate<<<TT * NE / 256, 256, 0, stream>>>(weights, indices, gate_w, counts);
  k_scan<<<1, 64, 0, stream>>>(counts, offs);
  k_fill<<<TT * NE / 256, 256, 0, stream>>>(gate_w, offs, cursor, slot_tok, slot_gate,
                                            tcnt, tok_slots);
  k_cast_h1<<<2048, 256, 0, stream>>>(x, xb, Wg, wgb, Wu, wub);
  // gemm1A: experts 0-7; embedded cast of Wg[8:16], Wu[8:16]
  k_gemm1<<<2112, 256, 0, stream>>>(xb, wgb, wub,
                                    Wg, wgb, HOFF, Wu, wub, HOFF, /*eBase=*/0,
                                    slot_tok, slot_gate, offs, counts, act);
  // gemm1B: experts 8-15; embedded cast of Wd (both halves)
  k_gemm1<<<2112, 256, 0, stream>>>(xb, wgb, wub,
                                    Wd, wdb, 0, Wd, wdb, HOFF, /*eBase=*/8,
                                    slot_tok, slot_gate, offs, counts, act);
  k_gemm2<<<4096, 256, 0, stream>>>(act, wdb, slot_tok, offs, counts, y,
                                    useCombine ? outb : (u16*)nullptr);
  if (useCombine) {
    k_combine<<<TT * DMODEL / 8 / 256, 256, 0, stream>>>(outb, tok_slots, tcnt, y);
  }
}

// Round 21
// 551.545 us; speedup vs baseline: 1.0425x; 1.0425x over previous
//
#include <hip/hip_runtime.h>
#include <hip/hip_bf16.h>
#include <cstdint>

// Problem constants (from reference)
#define TT     2048   // tokens
#define KSEL   6      // experts per token
#define DMODEL 2048   // model dim
#define DINTER 1408   // moe intermediate dim
#define NE     16     // routed experts
#define PMAX   (TT * KSEL)

typedef short bf16x8 __attribute__((ext_vector_type(8)));
typedef float f32x4 __attribute__((ext_vector_type(4)));
typedef unsigned short u16;
typedef u16 u16x8 __attribute__((ext_vector_type(8)));

__device__ __forceinline__ u16 f2bf(float f) {
  union { float f; unsigned u; } v; v.f = f;
  return (u16)((v.u + 0x7FFFu + ((v.u >> 16) & 1u)) >> 16);  // RNE
}
__device__ __forceinline__ float bf2f(u16 h) {
  union { unsigned u; float f; } v; v.u = (unsigned)h << 16; return v.f;
}

__device__ __forceinline__ void gl2lds16(const void* g, void* l) {
  __builtin_amdgcn_global_load_lds((const __attribute__((address_space(1))) void*)g,
                                   (__attribute__((address_space(3))) void*)l,
                                   16, 0, 0);
}

// gate_w[t,e] = sum_k weights[t,k]*(indices[t,k]==e); count routed (t,e) pairs
__global__ void k_gate(const float* __restrict__ w, const int* __restrict__ idx,
                       float* __restrict__ gate_w, int* __restrict__ counts) {
  int g = blockIdx.x * 256 + threadIdx.x;  // T*E threads
  int t = g >> 4, e = g & 15;
  const int* ip = idx + t * KSEL;
  const float* wp = w + t * KSEL;
  float s = 0.f;
#pragma unroll
  for (int k = 0; k < KSEL; ++k) s += (ip[k] == e) ? wp[k] : 0.f;
  gate_w[g] = s;
  if (s != 0.f) atomicAdd(counts + e, 1);
}

__global__ void k_scan(const int* __restrict__ counts, int* __restrict__ offs) {
  if (threadIdx.x == 0 && blockIdx.x == 0) {
    int r = 0;
#pragma unroll
    for (int e = 0; e < NE; ++e) { offs[e] = r; r += counts[e]; }
    offs[NE] = r;
  }
}

// fill slot lists + per-token slot map (for the combine epilogue)
__global__ void k_fill(const float* __restrict__ gate_w, const int* __restrict__ offs,
                       int* __restrict__ cursor, int* __restrict__ slot_tok,
                       float* __restrict__ slot_gate, int* __restrict__ tcnt,
                       int* __restrict__ tok_slots) {
  int g = blockIdx.x * 256 + threadIdx.x;
  int t = g >> 4, e = g & 15;
  float s = gate_w[g];
  if (s != 0.f) {
    int p = atomicAdd(cursor + e, 1);
    int sl = offs[e] + p;
    slot_tok[sl] = t;
    slot_gate[sl] = s;
    int q = atomicAdd(tcnt + t, 1);
    tok_slots[t * KSEL + q] = sl;
  }
}

// fp32->bf16 cast for x + Wg + Wu (Wd is cast inside the gemm1 launch)
#define XV8   (TT * DMODEL / 8)                      // 524288
#define WV8   (NE * DINTER * DMODEL / 8)             // 5767168
__global__ void k_cast3(const float* __restrict__ x,  u16* __restrict__ xb,
                        const float* __restrict__ wg, u16* __restrict__ wgb,
                        const float* __restrict__ wu, u16* __restrict__ wub) {
  const int total = XV8 + 2 * WV8;
  int stride = gridDim.x * 256;
  for (int i = blockIdx.x * 256 + threadIdx.x; i < total; i += stride) {
    const float* src; u16* dst; int j;
    if (i < XV8)            { src = x;  dst = xb;  j = i; }
    else if (i < XV8 + WV8) { src = wg; dst = wgb; j = i - XV8; }
    else                    { src = wu; dst = wub; j = i - XV8 - WV8; }
    const float4* p = (const float4*)src + (size_t)j * 2;
    float4 v0 = p[0], v1 = p[1];
    u16x8 o;
    o[0] = f2bf(v0.x); o[1] = f2bf(v0.y); o[2] = f2bf(v0.z); o[3] = f2bf(v0.w);
    o[4] = f2bf(v1.x); o[5] = f2bf(v1.y); o[6] = f2bf(v1.z); o[7] = f2bf(v1.w);
    *(u16x8*)(dst + (size_t)j * 8) = o;
  }
}

// ---------------------------------------------------------------------------
// LDS XOR swizzle (G4 / rule #21): rows are 64 bf16 = 8 16B-units; write side
// pre-permutes the GLOBAL source unit (u' = u ^ (row&7), LDS dest linear per
// gl2lds HW rule), read side applies the same XOR -> conflict-free (R6: 0).
// Register budget (m69): 128 AGPR acc + ~108 VGPR = 2 waves/SIMD for gemm1;
// gemm2 (64 AGPR) fits (256,3). (256,3)+128 AGPR spills (R15).
// ---------------------------------------------------------------------------

// GEMM1 (R6 core) + embedded castWd role blocks (R19-validated: total win ~-24us,
// cast traffic rides gemm1's idle memory window; R20's further split regressed).
// Grid = 3520 = 440 octets of 8; octets with (q%5==4) are castWd (704 blocks),
// the rest decode to the 2816 gemm work-ids. Octet interleave keeps b%8==g%8,
// preserving the XCD-chunk property.
__global__ __launch_bounds__(256, 2) void k_gemm1(
    const u16* __restrict__ xb, const u16* __restrict__ wgb, const u16* __restrict__ wub,
    const float* __restrict__ Wd, u16* __restrict__ wdb,
    const int* __restrict__ slot_tok, const float* __restrict__ slot_gate,
    const int* __restrict__ offs, const int* __restrict__ counts,
    u16* __restrict__ act) {
  int bq = blockIdx.x >> 3, br = blockIdx.x & 7;
  if (bq % 5 == 4) {
    // ---- castWd role: 704 blocks x 8192 items x 8 elems ----
    int c = (bq / 5) * 8 + br;
    int base = c * 8192;
#pragma unroll 4
    for (int it = 0; it < 32; ++it) {
      int j = base + it * 256 + threadIdx.x;
      const float4* p = (const float4*)Wd + (size_t)j * 2;
      float4 v0 = p[0], v1 = p[1];
      u16x8 o;
      o[0] = f2bf(v0.x); o[1] = f2bf(v0.y); o[2] = f2bf(v0.z); o[3] = f2bf(v0.w);
      o[4] = f2bf(v1.x); o[5] = f2bf(v1.y); o[6] = f2bf(v1.z); o[7] = f2bf(v1.w);
      *(u16x8*)(wdb + (size_t)j * 8) = o;
    }
    return;
  }
  int g = ((bq / 5) * 4 + (bq % 5)) * 8 + br;       // [0, 2816)
  // XCD-chunked swizzle: w = (g&7)*352 + g>>3
  int w = (g & 7) * 352 + (g >> 3);
  int mt = w & 15, rest = w >> 4;
  int it = rest % 11, e = rest / 11;

  int mcount = counts[e];
  if (mt * 128 >= mcount) return;
  int mrem = mcount - mt * 128; if (mrem > 128) mrem = 128;
  int slotBase = offs[e] + mt * 128;
  int iBase = it * 128;

  __shared__ u16 sA[128 * 64];
  __shared__ u16 sG[128 * 64];
  __shared__ u16 sU[128 * 64];
  __shared__ int tokLds[128];
  __shared__ float gateLds[128];

  int tid = threadIdx.x;
  if (tid < 128) {
    int rl = tid < mrem ? tid : 0;        // pad rows clamp to row 0 (valid addr)
    tokLds[tid] = slot_tok[slotBase + rl];
    gateLds[tid] = (tid < mrem) ? slot_gate[slotBase + rl] : 0.f;
  }
  __syncthreads();

  int wv = tid >> 6, lane = tid & 63;
  // staging: 16 chunks of 1KB (8 rows x 128B); linear LDS dest, swizzled source
  const u16 *aSrc[4], *gSrc[4], *uSrc[4];
  u16 *aDst[4], *gDst[4], *uDst[4];
  const u16* gBase = wgb + ((size_t)e * DINTER + iBase) * DMODEL;
  const u16* uBase = wub + ((size_t)e * DINTER + iBase) * DMODEL;
  int r8 = lane >> 3;
  int colOff = ((lane & 7) ^ r8) * 8;   // swizzled 16B-unit within the row
#pragma unroll
  for (int i2 = 0; i2 < 4; ++i2) {
    int chunk = wv * 4 + i2;
    int row = chunk * 8 + r8;
    aSrc[i2] = xb + (size_t)tokLds[row] * DMODEL + colOff;
    gSrc[i2] = gBase + (size_t)row * DMODEL + colOff;
    uSrc[i2] = uBase + (size_t)row * DMODEL + colOff;
    aDst[i2] = sA + chunk * 512;
    gDst[i2] = sG + chunk * 512;
    uDst[i2] = sU + chunk * 512;
  }

  f32x4 accg[4][4] = {};
  f32x4 accu[4][4] = {};
  int fr = lane & 15, fq = lane >> 4;
  int wr = (wv >> 1) * 64, wc = (wv & 1) * 64;

  for (int kb = 0; kb < DMODEL / 64; ++kb) {
    int kOff = kb * 64;
    __syncthreads();
#pragma unroll
    for (int i2 = 0; i2 < 4; ++i2) {
      gl2lds16(aSrc[i2] + kOff, aDst[i2]);
      gl2lds16(gSrc[i2] + kOff, gDst[i2]);
      gl2lds16(uSrc[i2] + kOff, uDst[i2]);
    }
    __syncthreads();
#pragma unroll
    for (int kf = 0; kf < 2; ++kf) {
      bf16x8 af[4], bg[4], bu[4];
#pragma unroll
      for (int mf = 0; mf < 4; ++mf) {
        int row = wr + mf * 16 + fr;
        int cu = ((kf * 4 + fq) ^ (row & 7)) * 8;
        af[mf] = *(const bf16x8*)&sA[row * 64 + cu];
      }
#pragma unroll
      for (int nf = 0; nf < 4; ++nf) {
        int row = wc + nf * 16 + fr;
        int cu = ((kf * 4 + fq) ^ (row & 7)) * 8;
        bg[nf] = *(const bf16x8*)&sG[row * 64 + cu];
        bu[nf] = *(const bf16x8*)&sU[row * 64 + cu];
      }
#pragma unroll
      for (int mf = 0; mf < 4; ++mf)
#pragma unroll
        for (int nf = 0; nf < 4; ++nf) {
          accg[mf][nf] = __builtin_amdgcn_mfma_f32_16x16x32_bf16(af[mf], bg[nf], accg[mf][nf], 0, 0, 0);
          accu[mf][nf] = __builtin_amdgcn_mfma_f32_16x16x32_bf16(af[mf], bu[nf], accu[mf][nf], 0, 0, 0);
        }
    }
  }
  // epilogue: act = silu(g)*u*gate -> bf16  (D layout: col=lane&15, row=(lane>>4)*4+r)
#pragma unroll
  for (int mf = 0; mf < 4; ++mf)
#pragma unroll
    for (int nf = 0; nf < 4; ++nf)
#pragma unroll
      for (int r = 0; r < 4; ++r) {
        int row = wr + mf * 16 + fq * 4 + r;
        if (row < mrem) {
          float gv = accg[mf][nf][r], uv = accu[mf][nf][r];
          float a = gv / (1.f + __expf(-gv)) * uv * gateLds[row];
          act[(size_t)(slotBase + row) * DINTER + iBase + wc + nf * 16 + fr] = f2bf(a);
        }
      }
}

// GEMM2: per-slot contribution out[slot,:] = act[slot,:] @ Wd[e,:,:]^T.
// Combine path (outb != nullptr): plain bf16 stores, NO atomics; k_combine
// sums each token's <=6 slots. Fallback (outb == nullptr): fp32 atomicAdd.
__global__ __launch_bounds__(256, 3) void k_gemm2(
    const u16* __restrict__ act, const u16* __restrict__ wdb,
    const int* __restrict__ slot_tok, const int* __restrict__ offs,
    const int* __restrict__ counts, float* __restrict__ y,
    u16* __restrict__ outb) {
  // grid flat = 16(mt) x 16(dt) x 16(e) = 4096 = 8*512
  int b = blockIdx.x;
  int w = (b & 7) * 512 + (b >> 3);
  int mt = w & 15, rest = w >> 4;
  int dt = rest & 15, e = rest >> 4;

  int mcount = counts[e];
  if (mt * 128 >= mcount) return;
  int mrem = mcount - mt * 128; if (mrem > 128) mrem = 128;
  int slotBase = offs[e] + mt * 128;
  int dBase = dt * 128;

  __shared__ u16 sA[128 * 64];
  __shared__ u16 sB[128 * 64];
  __shared__ int tokLds[128];

  int tid = threadIdx.x;
  if (tid < 128) tokLds[tid] = slot_tok[slotBase + (tid < mrem ? tid : 0)];
  __syncthreads();

  int wv = tid >> 6, lane = tid & 63;
  const u16 *aSrc[4], *bSrc[4];
  u16 *aDst[4], *bDst[4];
  const u16* bBase = wdb + ((size_t)e * DMODEL + dBase) * DINTER;
  int r8 = lane >> 3;
  int colOff = ((lane & 7) ^ r8) * 8;   // swizzled 16B-unit
#pragma unroll
  for (int i2 = 0; i2 < 4; ++i2) {
    int chunk = wv * 4 + i2;
    int row = chunk * 8 + r8;
    aSrc[i2] = act + (size_t)(slotBase + row) * DINTER + colOff;  // act padded rows
    bSrc[i2] = bBase + (size_t)row * DINTER + colOff;
    aDst[i2] = sA + chunk * 512;
    bDst[i2] = sB + chunk * 512;
  }

  f32x4 acc[4][4] = {};
  int fr = lane & 15, fq = lane >> 4;
  int wr = (wv >> 1) * 64, wc = (wv & 1) * 64;

  for (int kb = 0; kb < DINTER / 64; ++kb) {
    int kOff = kb * 64;
    __syncthreads();
#pragma unroll
    for (int i2 = 0; i2 < 4; ++i2) {
      gl2lds16(aSrc[i2] + kOff, aDst[i2]);
      gl2lds16(bSrc[i2] + kOff, bDst[i2]);
    }
    __syncthreads();
#pragma unroll
    for (int kf = 0; kf < 2; ++kf) {
      bf16x8 af[4], bb[4];
#pragma unroll
      for (int mf = 0; mf < 4; ++mf) {
        int row = wr + mf * 16 + fr;
        int cu = ((kf * 4 + fq) ^ (row & 7)) * 8;
        af[mf] = *(const bf16x8*)&sA[row * 64 + cu];
      }
#pragma unroll
      for (int nf = 0; nf < 4; ++nf) {
        int row = wc + nf * 16 + fr;
        int cu = ((kf * 4 + fq) ^ (row & 7)) * 8;
        bb[nf] = *(const bf16x8*)&sB[row * 64 + cu];
      }
#pragma unroll
      for (int mf = 0; mf < 4; ++mf)
#pragma unroll
        for (int nf = 0; nf < 4; ++nf)
          acc[mf][nf] = __builtin_amdgcn_mfma_f32_16x16x32_bf16(af[mf], bb[nf], acc[mf][nf], 0, 0, 0);
    }
  }
#pragma unroll
  for (int mf = 0; mf < 4; ++mf)
#pragma unroll
    for (int nf = 0; nf < 4; ++nf)
#pragma unroll
      for (int r = 0; r < 4; ++r) {
        int row = wr + mf * 16 + fq * 4 + r;
        if (row < mrem) {
          int col = dBase + wc + nf * 16 + fr;
          if (outb) {
            outb[(size_t)(slotBase + row) * DMODEL + col] = f2bf(acc[mf][nf][r]);
          } else {
            atomicAdd(y + (size_t)tokLds[row] * DMODEL + col, acc[mf][nf][r]);
          }
        }
      }
}

// combine: y[t,:] = sum over token t's slots of out[slot,:]
__global__ void k_combine(const u16* __restrict__ outb, const int* __restrict__ tok_slots,
                          const int* __restrict__ tcnt, float* __restrict__ y) {
  int idx = blockIdx.x * 256 + threadIdx.x;   // TT * DMODEL/8 threads
  int t = idx >> 8;                           // DMODEL/8 = 256 per token
  int d0 = (idx & 255) * 8;
  int n = tcnt[t];
  float s[8] = {};
  for (int j = 0; j < n; ++j) {
    int sl = tok_slots[t * KSEL + j];
    u16x8 v = *(const u16x8*)(outb + (size_t)sl * DMODEL + d0);
#pragma unroll
    for (int q = 0; q < 8; ++q) s[q] += bf2f(v[q]);
  }
  float4* yp = (float4*)(y + (size_t)t * DMODEL + d0);
  yp[0] = make_float4(s[0], s[1], s[2], s[3]);
  yp[1] = make_float4(s[4], s[5], s[6], s[7]);
}

extern "C" void kernel_launch(void* const* d_in, const int* in_sizes, int n_in,
                              void* d_out, int out_size, void* d_ws, size_t ws_size,
                              hipStream_t stream) {
  const float* x       = (const float*)d_in[0];
  const float* weights = (const float*)d_in[1];
  const int*   indices = (const int*)d_in[2];
  const float* Wg      = (const float*)d_in[3];
  const float* Wu      = (const float*)d_in[4];
  const float* Wd      = (const float*)d_in[5];
  float* y = (float*)d_out;

  const size_t WELEM = (size_t)NE * DINTER * DMODEL;  // 46.1M elems per weight tensor

  char* ws = (char*)d_ws;
  size_t o = 0;
  float* gate_w = (float*)(ws + o); o += (size_t)TT * NE * 4;
  size_t ctrlOff = o;
  int* counts = (int*)(ws + o);
  int* offs   = (int*)(ws + o + 64);
  int* cursor = (int*)(ws + o + 192);
  int* tcnt   = (int*)(ws + o + 256);            // TT ints
  int* tok_slots = (int*)(ws + o + 256 + TT * 4); // TT*KSEL ints
  size_t ctrlZero = 256 + TT * 4;                // zero counts..tcnt
  o += 256 + TT * 4 + (size_t)TT * KSEL * 4;
  int*   slot_tok  = (int*)(ws + o);   o += (size_t)PMAX * 4;
  float* slot_gate = (float*)(ws + o); o += (size_t)PMAX * 4;
  u16* xb  = (u16*)(ws + o); o += (size_t)TT * DMODEL * 2;
  u16* act = (u16*)(ws + o); o += (size_t)(PMAX + 128) * DINTER * 2; // +128 pad rows
  u16* wgb = (u16*)(ws + o); o += WELEM * 2;
  u16* wub = (u16*)(ws + o); o += WELEM * 2;
  u16* wdb = (u16*)(ws + o); o += WELEM * 2;
  u16* outb = (u16*)(ws + o);
  size_t oEnd = o + (size_t)PMAX * DMODEL * 2;   // +50.3 MB for combine path
  bool useCombine = (ws_size >= oEnd);
  (void)in_sizes; (void)n_in;

  if (!useCombine) hipMemsetAsync(d_out, 0, (size_t)out_size * 4, stream);
  hipMemsetAsync(ws + ctrlOff, 0, ctrlZero, stream);

  k_gate<<<TT * NE / 256, 256, 0, stream>>>(weights, indices, gate_w, counts);
  k_scan<<<1, 64, 0, stream>>>(counts, offs);
  k_fill<<<TT * NE / 256, 256, 0, stream>>>(gate_w, offs, cursor, slot_tok, slot_gate,
                                            tcnt, tok_slots);
  k_cast3<<<2048, 256, 0, stream>>>(x, xb, Wg, wgb, Wu, wub);
  k_gemm1<<<3520, 256, 0, stream>>>(xb, wgb, wub, Wd, wdb, slot_tok, slot_gate,
                                    offs, counts, act);
  k_gemm2<<<4096, 256, 0, stream>>>(act, wdb, slot_tok, offs, counts, y,
                                    useCombine ? outb : (u16*)nullptr);
  if (useCombine) {
    k_combine<<<TT * DMODEL / 8 / 256, 256, 0, stream>>>(outb, tok_slots, tcnt, y);
  }
}